// Round 3
// baseline (718.821 us; speedup 1.0000x reference)
//
#include <hip/hip_runtime.h>
#include <hip/hip_bf16.h>
#include <stdint.h>

// DynamicSparseAttention MI355X r3 — fp32 I/O.
// Precision strategy: 3-way bf16 split (h+m+l captures all 24 fp32 mantissa
// bits) + 6-product MFMA (hh,hm,mh,hl,lh,mm) with dual accumulators for the
// Q/K path (scores drive an exact top-64 -> flips vs np ref must be at/below
// np's own fp32 noise). V and O paths use 3-product (h,m) — their error
// enters the output linearly at ~1e-7, irrelevant vs 5.78e-3 threshold.

typedef __bf16 bf16_t;
typedef bf16_t bf16x8 __attribute__((ext_vector_type(8)));
typedef bf16_t bf16x4 __attribute__((ext_vector_type(4)));
typedef float  f32x4  __attribute__((ext_vector_type(4)));

#define NB 2
#define SS 1024
#define EE 1024
#define NH 16
#define HD 64
#define NBH (NB*NH)

__device__ __forceinline__ f32x4 mfma16(bf16x8 a, bf16x8 b, f32x4 c) {
  return __builtin_amdgcn_mfma_f32_16x16x32_bf16(a, b, c, 0, 0, 0);
}

// monotone key: larger float -> larger uint
__device__ __forceinline__ uint32_t fkey(float f) {
  uint32_t u = __float_as_uint(f);
  return (u & 0x80000000u) ? ~u : (u | 0x80000000u);
}

__device__ __forceinline__ void split3(float x, bf16_t& h, bf16_t& m, bf16_t& l) {
  h = (bf16_t)x;
  float r = x - (float)h;     // exact (Sterbenz-range)
  m = (bf16_t)r;
  float r2 = r - (float)m;    // exact
  l = (bf16_t)r2;             // residual <= 2^-27 |x|
}

// ---------------------------------------------------------------------------
// presplit: fp32 src -> h/m/l bf16 arrays (vectorized float4)
// ---------------------------------------------------------------------------
__global__ __launch_bounds__(256) void presplit(
    const float* __restrict__ src, bf16_t* __restrict__ h,
    bf16_t* __restrict__ m, bf16_t* __restrict__ l, int n4)
{
  int i = blockIdx.x * 256 + threadIdx.x;
  if (i >= n4) return;
  float4 v = ((const float4*)src)[i];
  float t[4] = { v.x, v.y, v.z, v.w };
  bf16x4 hv, mv, lv;
#pragma unroll
  for (int j = 0; j < 4; j++) {
    bf16_t a, b, c;
    split3(t[j], a, b, c);
    hv[j] = a; mv[j] = b; lv[j] = c;
  }
  ((bf16x4*)h)[i] = hv;
  ((bf16x4*)m)[i] = mv;
  ((bf16x4*)l)[i] = lv;
}

// ---------------------------------------------------------------------------
// NT GEMM on pre-split operands: C[m,n] = sum_k A[m,k]*W[n,k] + bias[n]
// M=2048, N=1024, K=1024. 64x64 tile, 4 waves (2x2 of 32x32), K-step 32.
// NT=6: products hh,hm,mh,hl,lh,mm (fp32-exact operands; q/k path)
// NT=3: products hh,hm,mh (v / o path)
// MODE 0: write 3-way-split bf16 h/m/l, layout [B,H,S,HD]   (q,k)
// MODE 1: write fp32, layout [B,H,S,HD]                      (v)
// MODE 2: write fp32 row-major [M,N]                          (final out)
// ---------------------------------------------------------------------------
template<int MODE, int NT>
__global__ __launch_bounds__(256) void gemm_pre(
    const bf16_t* __restrict__ Ah, const bf16_t* __restrict__ Am,
    const bf16_t* __restrict__ Al,
    const bf16_t* __restrict__ Bh, const bf16_t* __restrict__ Bm,
    const bf16_t* __restrict__ Bl,
    const float* __restrict__ bias,
    bf16_t* __restrict__ dH, bf16_t* __restrict__ dM, bf16_t* __restrict__ dL,
    float* __restrict__ dF)
{
  __shared__ bf16_t AsH[64 * 40], AsM[64 * 40], AsL[64 * 40];
  __shared__ bf16_t BsH[64 * 40], BsM[64 * 40], BsL[64 * 40];

  const int tid  = threadIdx.x;
  const int wv   = tid >> 6, lane = tid & 63;
  const int quad = lane >> 4, l16 = lane & 15;
  const int m0 = blockIdx.y * 64, n0 = blockIdx.x * 64;
  const int wm = (wv & 1) * 32, wn = (wv >> 1) * 32;
  const int srow = tid >> 2, scol = (tid & 3) * 8;

  f32x4 aH0[2][2] = {};   // hh accumulator, k < 512
  f32x4 aH1[2][2] = {};   // hh accumulator, k >= 512
  f32x4 aC [2][2] = {};   // correction terms (small magnitude)

  for (int k0 = 0; k0 < 1024; k0 += 32) {
    const size_t ao = (size_t)(m0 + srow) * 1024 + k0 + scol;
    const size_t bo = (size_t)(n0 + srow) * 1024 + k0 + scol;
    bf16x8 avh = *(const bf16x8*)(Ah + ao);
    bf16x8 avm = *(const bf16x8*)(Am + ao);
    bf16x8 bvh = *(const bf16x8*)(Bh + bo);
    bf16x8 bvm = *(const bf16x8*)(Bm + bo);
    bf16x8 avl, bvl;
    if (NT == 6) { avl = *(const bf16x8*)(Al + ao); bvl = *(const bf16x8*)(Bl + bo); }
    __syncthreads();                      // protect previous iter frag reads
    *(bf16x8*)(AsH + srow * 40 + scol) = avh;
    *(bf16x8*)(AsM + srow * 40 + scol) = avm;
    *(bf16x8*)(BsH + srow * 40 + scol) = bvh;
    *(bf16x8*)(BsM + srow * 40 + scol) = bvm;
    if (NT == 6) {
      *(bf16x8*)(AsL + srow * 40 + scol) = avl;
      *(bf16x8*)(BsL + srow * 40 + scol) = bvl;
    }
    __syncthreads();

    bf16x8 fAh[2], fAm[2], fAl[2], fBh[2], fBm[2], fBl[2];
#pragma unroll
    for (int t = 0; t < 2; t++) {
      fAh[t] = *(const bf16x8*)(AsH + (wm + t * 16 + l16) * 40 + quad * 8);
      fAm[t] = *(const bf16x8*)(AsM + (wm + t * 16 + l16) * 40 + quad * 8);
      fBh[t] = *(const bf16x8*)(BsH + (wn + t * 16 + l16) * 40 + quad * 8);
      fBm[t] = *(const bf16x8*)(BsM + (wn + t * 16 + l16) * 40 + quad * 8);
      if (NT == 6) {
        fAl[t] = *(const bf16x8*)(AsL + (wm + t * 16 + l16) * 40 + quad * 8);
        fBl[t] = *(const bf16x8*)(BsL + (wn + t * 16 + l16) * 40 + quad * 8);
      }
    }
    const bool hi = (k0 >= 512);
#pragma unroll
    for (int mt = 0; mt < 2; mt++)
#pragma unroll
    for (int nt = 0; nt < 2; nt++) {
      f32x4& H = hi ? aH1[mt][nt] : aH0[mt][nt];
      H = mfma16(fAh[mt], fBh[nt], H);
      aC[mt][nt] = mfma16(fAh[mt], fBm[nt], aC[mt][nt]);
      aC[mt][nt] = mfma16(fAm[mt], fBh[nt], aC[mt][nt]);
      if (NT == 6) {
        aC[mt][nt] = mfma16(fAh[mt], fBl[nt], aC[mt][nt]);
        aC[mt][nt] = mfma16(fAl[mt], fBh[nt], aC[mt][nt]);
        aC[mt][nt] = mfma16(fAm[mt], fBm[nt], aC[mt][nt]);
      }
    }
  }

  // epilogue: D[row=quad*4+r][col=l16]
#pragma unroll
  for (int mt = 0; mt < 2; mt++)
#pragma unroll
  for (int nt = 0; nt < 2; nt++)
#pragma unroll
  for (int r  = 0; r  < 4;  r++) {
    int gm = m0 + wm + mt * 16 + quad * 4 + r;
    int gn = n0 + wn + nt * 16 + l16;
    float v = (aH0[mt][nt][r] + aH1[mt][nt][r]) + aC[mt][nt][r] + bias[gn];
    if (MODE == 2) {
      dF[(size_t)gm * 1024 + gn] = v;
    } else {
      int b_ = gm >> 10, s_ = gm & 1023, h_ = gn >> 6, d_ = gn & 63;
      size_t di = (((size_t)b_ * NH + h_) * SS + s_) * HD + d_;
      if (MODE == 1) {
        dF[di] = v;
      } else {
        bf16_t hh, mm, ll;
        split3(v, hh, mm, ll);
        dH[di] = hh; dM[di] = mm; dL[di] = ll;
      }
    }
  }
}

// ---------------------------------------------------------------------------
// Fused attention: per WG = one (b,h) x 16 queries.
// 6-product split MFMA scores (fp32-grade) -> exact top-64 radix select
// (jax lowest-index tie-break) -> softmax(64) -> fp32 PV -> split-2 write.
// ---------------------------------------------------------------------------
__global__ __launch_bounds__(256) void attn_topk(
    const bf16_t* __restrict__ qhg, const bf16_t* __restrict__ qmg,
    const bf16_t* __restrict__ qlg,
    const bf16_t* __restrict__ khg, const bf16_t* __restrict__ kmg,
    const bf16_t* __restrict__ klg,
    const float*  __restrict__ vg,
    bf16_t* __restrict__ attnH, bf16_t* __restrict__ attnM)
{
  __shared__ float   sc[16 * 1028];    // fp32 scores, padded rows (65792 B)
  __shared__ bf16_t  kH[128 * 72], kM[128 * 72], kL[128 * 72];  // 55296 B
  __shared__ bf16_t  qH[16 * 72],  qM[16 * 72],  qL[16 * 72];   // 6912 B
  __shared__ uint32_t hist[4 * 256];   // per-wave radix histograms (4096 B)
  __shared__ int     selIdx[16 * 64];  // 4096 B
  __shared__ float   selW[16 * 64];    // 4096 B

  const int tid  = threadIdx.x;
  const int wv   = tid >> 6, lane = tid & 63;
  const int quad = lane >> 4, l16 = lane & 15;
  const int bh = blockIdx.x >> 6;          // 0..31
  const int qt = blockIdx.x & 63;
  const int b_ = bh >> 4, h_ = bh & 15;
  const int q0 = qt * 16;

  // stage q h/m/l (16 rows x 64 bf16)
  if (tid < 128) {
    int row = tid >> 3, c8 = (tid & 7) * 8;
    size_t g = ((size_t)bh * SS + q0 + row) * HD + c8;
    *(bf16x8*)(qH + row * 72 + c8) = *(const bf16x8*)(qhg + g);
    *(bf16x8*)(qM + row * 72 + c8) = *(const bf16x8*)(qmg + g);
    *(bf16x8*)(qL + row * 72 + c8) = *(const bf16x8*)(qlg + g);
  }
  __syncthreads();

  bf16x8 aH[2], aM[2], aL[2];
#pragma unroll
  for (int ks = 0; ks < 2; ks++) {
    aH[ks] = *(const bf16x8*)(qH + l16 * 72 + ks * 32 + quad * 8);
    aM[ks] = *(const bf16x8*)(qM + l16 * 72 + ks * 32 + quad * 8);
    aL[ks] = *(const bf16x8*)(qL + l16 * 72 + ks * 32 + quad * 8);
  }

  // ---- score phase: 8 chunks of 128 keys ----
  for (int kc = 0; kc < 8; kc++) {
    uint4 th[4], tm[4], tl[4];
    size_t gbase = ((size_t)bh * SS + kc * 128) * HD;   // bf16 elems
#pragma unroll
    for (int r = 0; r < 4; r++) {
      int g = r * 256 + tid;                            // 16B units (1024 total)
      th[r] = *(const uint4*)(khg + gbase + (size_t)g * 8);
      tm[r] = *(const uint4*)(kmg + gbase + (size_t)g * 8);
      tl[r] = *(const uint4*)(klg + gbase + (size_t)g * 8);
    }
    __syncthreads();                                    // protect prev chunk frag reads
#pragma unroll
    for (int r = 0; r < 4; r++) {
      int g = r * 256 + tid;
      int row = g >> 3, c8 = (g & 7) * 8;
      *(uint4*)(kH + row * 72 + c8) = th[r];
      *(uint4*)(kM + row * 72 + c8) = tm[r];
      *(uint4*)(kL + row * 72 + c8) = tl[r];
    }
    __syncthreads();
#pragma unroll
    for (int t2 = 0; t2 < 2; t2++) {
      int k16 = (wv * 2 + t2) * 16;
      const bf16_t* rH = kH + (k16 + l16) * 72 + quad * 8;
      const bf16_t* rM = kM + (k16 + l16) * 72 + quad * 8;
      const bf16_t* rL = kL + (k16 + l16) * 72 + quad * 8;
      bf16x8 bH0 = *(const bf16x8*)(rH),      bH1 = *(const bf16x8*)(rH + 32);
      bf16x8 bM0 = *(const bf16x8*)(rM),      bM1 = *(const bf16x8*)(rM + 32);
      bf16x8 bL0 = *(const bf16x8*)(rL),      bL1 = *(const bf16x8*)(rL + 32);
      f32x4 accA = {}, accB = {}, accC = {};
      accA = mfma16(aH[0], bH0, accA);             // hh, k-chunk 0
      accB = mfma16(aH[1], bH1, accB);             // hh, k-chunk 1
      accC = mfma16(aH[0], bM0, accC);             // hm
      accC = mfma16(aH[1], bM1, accC);
      accC = mfma16(aM[0], bH0, accC);             // mh
      accC = mfma16(aM[1], bH1, accC);
      accC = mfma16(aH[0], bL0, accC);             // hl
      accC = mfma16(aH[1], bL1, accC);
      accC = mfma16(aL[0], bH0, accC);             // lh
      accC = mfma16(aL[1], bH1, accC);
      accC = mfma16(aM[0], bM0, accC);             // mm
      accC = mfma16(aM[1], bM1, accC);
      int key = kc * 128 + k16 + l16;
#pragma unroll
      for (int r = 0; r < 4; r++)
        sc[(quad * 4 + r) * 1028 + key] = ((accA[r] + accB[r]) + accC[r]) * 0.125f;
    }
    __syncthreads();
  }

  // ---- selection + softmax: wave wv handles queries wv, wv+4, wv+8, wv+12 ----
  uint32_t* histw = hist + wv * 256;
  const uint64_t lt = (1ull << lane) - 1ull;
  for (int qi = 0; qi < 4; qi++) {
    int q = qi * 4 + wv;
    float* row = sc + q * 1028;
    uint32_t prefix = 0, pmask = 0;
    int needed = 64;
    for (int rnd = 0; rnd < 4; rnd++) {
      int shift = 24 - rnd * 8;
      *(uint4*)(histw + lane * 4) = uint4{0, 0, 0, 0};
      __syncthreads();
      for (int i = 0; i < 16; i++) {
        uint32_t u = fkey(row[i * 64 + lane]);
        if ((u & pmask) == prefix) atomicAdd(histw + ((u >> shift) & 255u), 1u);
      }
      __syncthreads();
      // descending cumulative scan: lane covers bins 255-4l .. 252-4l
      uint4 hv = *(const uint4*)(histw + (252 - lane * 4));
      uint32_t s_l = hv.x + hv.y + hv.z + hv.w;
      uint32_t x = s_l;
#pragma unroll
      for (int off = 1; off < 64; off <<= 1) {
        uint32_t y = __shfl_up(x, off);
        if (lane >= off) x += y;
      }
      uint32_t P = x - s_l;  // count in bins strictly above this lane's range
      uint32_t harr[4] = { hv.w, hv.z, hv.y, hv.x };  // c=0 -> bin 255-4l
      uint32_t cb = P, G = 0;
      int foundc = -1;
#pragma unroll
      for (int c = 0; c < 4; c++) {
        uint32_t hc = harr[c];
        if (foundc < 0 && (int)cb < needed && (int)(cb + hc) >= needed) {
          foundc = c; G = cb;
        }
        cb += hc;
      }
      uint64_t fm = __ballot(foundc >= 0);
      int src = __ffsll((unsigned long long)fm) - 1;
      int vstar = __shfl((foundc >= 0) ? (255 - lane * 4 - foundc) : 0, src);
      int Gs    = __shfl((int)G, src);
      needed -= Gs;
      prefix |= ((uint32_t)vstar) << shift;
      pmask  |= 0xFFu << shift;
      __syncthreads();
    }
    // gather: u>T always; u==T taken in ascending index order (jax tie-break)
    int selTotal = 0, eqTaken = 0;
    for (int i = 0; i < 16; i++) {
      int idx = i * 64 + lane;
      float f = row[idx];
      uint32_t u = fkey(f);
      bool isG = u > prefix, isE = (u == prefix);
      uint64_t em = __ballot(isE);
      int eqrank = eqTaken + (int)__popcll(em & lt);
      bool s_ = isG || (isE && eqrank < needed);
      uint64_t sm = __ballot(s_);
      int pos = selTotal + (int)__popcll(sm & lt);
      if (s_) { selIdx[q * 64 + pos] = idx; selW[q * 64 + pos] = f; }
      selTotal += (int)__popcll(sm);
      eqTaken  += (int)__popcll(em);
    }
    __syncthreads();
    // softmax over the 64 selected scores
    float sv = selW[q * 64 + lane];
    float mx = sv;
#pragma unroll
    for (int off = 32; off >= 1; off >>= 1) mx = fmaxf(mx, __shfl_xor(mx, off));
    float e = __expf(sv - mx);
    float sum = e;
#pragma unroll
    for (int off = 32; off >= 1; off >>= 1) sum += __shfl_xor(sum, off);
    selW[q * 64 + lane] = e / sum;
    __syncthreads();
  }
  __syncthreads();

  // ---- PV: thread t -> (q = t>>4, d-block = (t&15)*4), v fp32; split-2 out --
  {
    int q = tid >> 4, dblk = (tid & 15) * 4;
    const float* vb = vg + (size_t)bh * SS * HD;
    f32x4 a4 = {};
    for (int j = 0; j < 64; j++) {
      float w = selW[q * 64 + j];
      int  idx = selIdx[q * 64 + j];
      f32x4 v4 = *(const f32x4*)(vb + (size_t)idx * HD + dblk);
      a4 += w * v4;
    }
    size_t dofs = ((size_t)b_ * SS + q0 + q) * EE + h_ * HD + dblk;
    bf16x4 oh, om;
#pragma unroll
    for (int j = 0; j < 4; j++) {
      bf16_t hh = (bf16_t)a4[j];
      oh[j] = hh;
      om[j] = (bf16_t)(a4[j] - (float)hh);
    }
    *(bf16x4*)(attnH + dofs) = oh;
    *(bf16x4*)(attnM + dofs) = om;
  }
}

// ---------------------------------------------------------------------------
extern "C" void kernel_launch(void* const* d_in, const int* in_sizes, int n_in,
                              void* d_out, int out_size, void* d_ws, size_t ws_size,
                              hipStream_t stream)
{
  const float* x  = (const float*)d_in[0];
  const float* Wq = (const float*)d_in[1];
  const float* bq = (const float*)d_in[2];
  const float* Wk = (const float*)d_in[3];
  const float* bk = (const float*)d_in[4];
  const float* Wv = (const float*)d_in[5];
  const float* bv = (const float*)d_in[6];
  const float* Wo = (const float*)d_in[7];
  const float* bo = (const float*)d_in[8];

  const size_t NX = (size_t)NB * SS * EE;   // 2M elems (x, q, k, v, attn)
  const size_t NW = (size_t)EE * EE;        // 1M elems (weights)

  char* p = (char*)d_ws;
  auto takeb = [&](size_t n) { bf16_t* r = (bf16_t*)p; p += n * sizeof(bf16_t); return r; };
  auto takef = [&](size_t n) { float*  r = (float*)p;  p += n * sizeof(float);  return r; };

  bf16_t *xh = takeb(NX), *xm = takeb(NX), *xl = takeb(NX);
  bf16_t *wqh = takeb(NW), *wqm = takeb(NW), *wql = takeb(NW);
  bf16_t *wkh = takeb(NW), *wkm = takeb(NW), *wkl = takeb(NW);
  bf16_t *wvh = takeb(NW), *wvm = takeb(NW), *wvl = takeb(NW);
  bf16_t *woh = takeb(NW), *wom = takeb(NW), *wol = takeb(NW);
  bf16_t *qh = takeb(NX), *qm = takeb(NX), *ql = takeb(NX);
  bf16_t *kh = takeb(NX), *km = takeb(NX), *kl = takeb(NX);
  float  *vws = takef(NX);
  bf16_t *ath = takeb(NX), *atm = takeb(NX);

  dim3 blk(256);
  presplit<<<dim3((NX / 4 + 255) / 256), blk, 0, stream>>>(x,  xh,  xm,  xl,  NX / 4);
  presplit<<<dim3((NW / 4 + 255) / 256), blk, 0, stream>>>(Wq, wqh, wqm, wql, NW / 4);
  presplit<<<dim3((NW / 4 + 255) / 256), blk, 0, stream>>>(Wk, wkh, wkm, wkl, NW / 4);
  presplit<<<dim3((NW / 4 + 255) / 256), blk, 0, stream>>>(Wv, wvh, wvm, wvl, NW / 4);
  presplit<<<dim3((NW / 4 + 255) / 256), blk, 0, stream>>>(Wo, woh, wom, wol, NW / 4);

  dim3 gg(EE / 64, (NB * SS) / 64);                 // 16 x 32 tiles
  gemm_pre<0, 6><<<gg, blk, 0, stream>>>(xh, xm, xl, wqh, wqm, wql, bq,
                                         qh, qm, ql, nullptr);
  gemm_pre<0, 6><<<gg, blk, 0, stream>>>(xh, xm, xl, wkh, wkm, wkl, bk,
                                         kh, km, kl, nullptr);
  gemm_pre<1, 3><<<gg, blk, 0, stream>>>(xh, xm, xl, wvh, wvm, wvl, bv,
                                         nullptr, nullptr, nullptr, vws);

  attn_topk<<<dim3(NBH * (SS / 16)), blk, 0, stream>>>(qh, qm, ql, kh, km, kl,
                                                       vws, ath, atm);

  gemm_pre<2, 3><<<gg, blk, 0, stream>>>(ath, atm, nullptr, woh, wom, wol, bo,
                                         nullptr, nullptr, nullptr, (float*)d_out);
}

// Round 4
// 450.544 us; speedup vs baseline: 1.5955x; 1.5955x over previous
//
#include <hip/hip_runtime.h>
#include <hip/hip_bf16.h>
#include <stdint.h>

// DynamicSparseAttention MI355X r4 — fp32 I/O.
// r3 passed (absmax 9.8e-4). r4 = attn occupancy attack:
//   - k/q LDS staging removed (direct global->VGPR MFMA frags, L2-resident)
//   - 8 queries/WG (sc LDS halved): LDS 153KB -> 40KB => 3 WG/CU (was 1)
//   - per-lane score values hoisted to registers for the radix rounds
//   - wave-local fences instead of full barriers in selection
//   - 5 presplit launches fused into 1
// GEMMs unchanged from r3 (next round's target).

typedef __bf16 bf16_t;
typedef bf16_t bf16x8 __attribute__((ext_vector_type(8)));
typedef bf16_t bf16x4 __attribute__((ext_vector_type(4)));
typedef float  f32x4  __attribute__((ext_vector_type(4)));

#define NB 2
#define SS 1024
#define EE 1024
#define NH 16
#define HD 64
#define NBH (NB*NH)
#define NX_ ((size_t)NB*SS*EE)   // 2,097,152
#define NW_ ((size_t)EE*EE)      // 1,048,576

__device__ __forceinline__ f32x4 mfma16(bf16x8 a, bf16x8 b, f32x4 c) {
  return __builtin_amdgcn_mfma_f32_16x16x32_bf16(a, b, c, 0, 0, 0);
}

// monotone key: larger float -> larger uint
__device__ __forceinline__ uint32_t fkey(float f) {
  uint32_t u = __float_as_uint(f);
  return (u & 0x80000000u) ? ~u : (u | 0x80000000u);
}

__device__ __forceinline__ void split3(float x, bf16_t& h, bf16_t& m, bf16_t& l) {
  h = (bf16_t)x;
  float r = x - (float)h;     // exact
  m = (bf16_t)r;
  float r2 = r - (float)m;    // exact
  l = (bf16_t)r2;             // residual <= 2^-27 |x|
}

// wave-local LDS ordering fence (per-wave hist/sel; no cross-wave deps)
__device__ __forceinline__ void wave_fence() {
  __builtin_amdgcn_wave_barrier();
  __builtin_amdgcn_s_waitcnt(0);
  __builtin_amdgcn_wave_barrier();
}

// ---------------------------------------------------------------------------
// fused presplit of x, Wq, Wk, Wv, Wo into h/m/l limb arrays at fixed ws
// offsets.  blocks: [0,2048) x | +1024 each for Wq,Wk,Wv,Wo.  exact multiples.
// ---------------------------------------------------------------------------
__global__ __launch_bounds__(256) void presplit_all(
    const float* __restrict__ x,  const float* __restrict__ wq,
    const float* __restrict__ wk, const float* __restrict__ wv,
    const float* __restrict__ wo, bf16_t* __restrict__ base)
{
  const int blk = blockIdx.x;
  const float* src; bf16_t* h; size_t n; int i;
  if (blk < 2048)      { src = x;  h = base;                   n = NX_; i = blk;        }
  else if (blk < 3072) { src = wq; h = base + 3*NX_;           n = NW_; i = blk - 2048; }
  else if (blk < 4096) { src = wk; h = base + 3*NX_ + 3*NW_;   n = NW_; i = blk - 3072; }
  else if (blk < 5120) { src = wv; h = base + 3*NX_ + 6*NW_;   n = NW_; i = blk - 4096; }
  else                 { src = wo; h = base + 3*NX_ + 9*NW_;   n = NW_; i = blk - 5120; }
  bf16_t* m = h + n;
  bf16_t* l = m + n;
  int idx = i * 256 + threadIdx.x;            // float4 index
  float4 v = ((const float4*)src)[idx];
  float t[4] = { v.x, v.y, v.z, v.w };
  bf16x4 hv, mv, lv;
#pragma unroll
  for (int j = 0; j < 4; j++) {
    bf16_t a, b, c;
    split3(t[j], a, b, c);
    hv[j] = a; mv[j] = b; lv[j] = c;
  }
  ((bf16x4*)h)[idx] = hv;
  ((bf16x4*)m)[idx] = mv;
  ((bf16x4*)l)[idx] = lv;
}

// ---------------------------------------------------------------------------
// NT GEMM on pre-split operands (unchanged from r3, which passed)
// ---------------------------------------------------------------------------
template<int MODE, int NT>
__global__ __launch_bounds__(256) void gemm_pre(
    const bf16_t* __restrict__ Ah, const bf16_t* __restrict__ Am,
    const bf16_t* __restrict__ Al,
    const bf16_t* __restrict__ Bh, const bf16_t* __restrict__ Bm,
    const bf16_t* __restrict__ Bl,
    const float* __restrict__ bias,
    bf16_t* __restrict__ dH, bf16_t* __restrict__ dM, bf16_t* __restrict__ dL,
    float* __restrict__ dF)
{
  __shared__ bf16_t AsH[64 * 40], AsM[64 * 40], AsL[64 * 40];
  __shared__ bf16_t BsH[64 * 40], BsM[64 * 40], BsL[64 * 40];

  const int tid  = threadIdx.x;
  const int wv   = tid >> 6, lane = tid & 63;
  const int quad = lane >> 4, l16 = lane & 15;
  const int m0 = blockIdx.y * 64, n0 = blockIdx.x * 64;
  const int wm = (wv & 1) * 32, wn = (wv >> 1) * 32;
  const int srow = tid >> 2, scol = (tid & 3) * 8;

  f32x4 aH0[2][2] = {};   // hh accumulator, k < 512
  f32x4 aH1[2][2] = {};   // hh accumulator, k >= 512
  f32x4 aC [2][2] = {};   // correction terms (small magnitude)

  for (int k0 = 0; k0 < 1024; k0 += 32) {
    const size_t ao = (size_t)(m0 + srow) * 1024 + k0 + scol;
    const size_t bo = (size_t)(n0 + srow) * 1024 + k0 + scol;
    bf16x8 avh = *(const bf16x8*)(Ah + ao);
    bf16x8 avm = *(const bf16x8*)(Am + ao);
    bf16x8 bvh = *(const bf16x8*)(Bh + bo);
    bf16x8 bvm = *(const bf16x8*)(Bm + bo);
    bf16x8 avl, bvl;
    if (NT == 6) { avl = *(const bf16x8*)(Al + ao); bvl = *(const bf16x8*)(Bl + bo); }
    __syncthreads();                      // protect previous iter frag reads
    *(bf16x8*)(AsH + srow * 40 + scol) = avh;
    *(bf16x8*)(AsM + srow * 40 + scol) = avm;
    *(bf16x8*)(BsH + srow * 40 + scol) = bvh;
    *(bf16x8*)(BsM + srow * 40 + scol) = bvm;
    if (NT == 6) {
      *(bf16x8*)(AsL + srow * 40 + scol) = avl;
      *(bf16x8*)(BsL + srow * 40 + scol) = bvl;
    }
    __syncthreads();

    bf16x8 fAh[2], fAm[2], fAl[2], fBh[2], fBm[2], fBl[2];
#pragma unroll
    for (int t = 0; t < 2; t++) {
      fAh[t] = *(const bf16x8*)(AsH + (wm + t * 16 + l16) * 40 + quad * 8);
      fAm[t] = *(const bf16x8*)(AsM + (wm + t * 16 + l16) * 40 + quad * 8);
      fBh[t] = *(const bf16x8*)(BsH + (wn + t * 16 + l16) * 40 + quad * 8);
      fBm[t] = *(const bf16x8*)(BsM + (wn + t * 16 + l16) * 40 + quad * 8);
      if (NT == 6) {
        fAl[t] = *(const bf16x8*)(AsL + (wm + t * 16 + l16) * 40 + quad * 8);
        fBl[t] = *(const bf16x8*)(BsL + (wn + t * 16 + l16) * 40 + quad * 8);
      }
    }
    const bool hi = (k0 >= 512);
#pragma unroll
    for (int mt = 0; mt < 2; mt++)
#pragma unroll
    for (int nt = 0; nt < 2; nt++) {
      f32x4& H = hi ? aH1[mt][nt] : aH0[mt][nt];
      H = mfma16(fAh[mt], fBh[nt], H);
      aC[mt][nt] = mfma16(fAh[mt], fBm[nt], aC[mt][nt]);
      aC[mt][nt] = mfma16(fAm[mt], fBh[nt], aC[mt][nt]);
      if (NT == 6) {
        aC[mt][nt] = mfma16(fAh[mt], fBl[nt], aC[mt][nt]);
        aC[mt][nt] = mfma16(fAl[mt], fBh[nt], aC[mt][nt]);
        aC[mt][nt] = mfma16(fAm[mt], fBm[nt], aC[mt][nt]);
      }
    }
  }

  // epilogue: D[row=quad*4+r][col=l16]
#pragma unroll
  for (int mt = 0; mt < 2; mt++)
#pragma unroll
  for (int nt = 0; nt < 2; nt++)
#pragma unroll
  for (int r  = 0; r  < 4;  r++) {
    int gm = m0 + wm + mt * 16 + quad * 4 + r;
    int gn = n0 + wn + nt * 16 + l16;
    float v = (aH0[mt][nt][r] + aH1[mt][nt][r]) + aC[mt][nt][r] + bias[gn];
    if (MODE == 2) {
      dF[(size_t)gm * 1024 + gn] = v;
    } else {
      int b_ = gm >> 10, s_ = gm & 1023, h_ = gn >> 6, d_ = gn & 63;
      size_t di = (((size_t)b_ * NH + h_) * SS + s_) * HD + d_;
      if (MODE == 1) {
        dF[di] = v;
      } else {
        bf16_t hh, mm, ll;
        split3(v, hh, mm, ll);
        dH[di] = hh; dM[di] = mm; dL[di] = ll;
      }
    }
  }
}

// ---------------------------------------------------------------------------
// Fused attention r4: per WG = one (b,h) x 8 queries.  LDS = 40 KB.
// 6-product split MFMA scores (frags direct from global) -> exact top-64
// radix select (jax lowest-index tie-break) -> softmax(64) -> fp32 PV.
// ---------------------------------------------------------------------------
__global__ __launch_bounds__(256, 3) void attn_topk(
    const bf16_t* __restrict__ qhg, const bf16_t* __restrict__ qmg,
    const bf16_t* __restrict__ qlg,
    const bf16_t* __restrict__ khg, const bf16_t* __restrict__ kmg,
    const bf16_t* __restrict__ klg,
    const float*  __restrict__ vg,
    bf16_t* __restrict__ attnH, bf16_t* __restrict__ attnM)
{
  __shared__ float    sc[8 * 1028];       // 32896 B, stride 1028 (bank-safe)
  __shared__ uint32_t hist[4 * 256];      // per-wave radix histograms
  __shared__ ushort   selIdx[8 * 64];
  __shared__ float    selW[8 * 64];

  const int tid  = threadIdx.x;
  const int wv   = tid >> 6, lane = tid & 63;
  const int quad = lane >> 4, l16 = lane & 15;
  const int bh = blockIdx.x >> 7;          // 0..31 (128 q-tiles per bh)
  const int qt = blockIdx.x & 127;
  const int b_ = bh >> 4, h_ = bh & 15;
  const int q0 = qt * 8;

  // A-frags direct from global: lane holds q[m=l16][k=quad*8+j].
  // Only 8 valid queries; rows 8..15 clamp to row 7 (their C rows discarded).
  const int qrow = (l16 < 8) ? l16 : 7;
  const size_t qbase = ((size_t)bh * SS + q0 + qrow) * HD + quad * 8;
  bf16x8 aH[2], aM[2], aL[2];
#pragma unroll
  for (int ks = 0; ks < 2; ks++) {
    aH[ks] = *(const bf16x8*)(qhg + qbase + ks * 32);
    aM[ks] = *(const bf16x8*)(qmg + qbase + ks * 32);
    aL[ks] = *(const bf16x8*)(qlg + qbase + ks * 32);
  }

  // ---- score phase: 8 chunks of 128 keys, barrier-free pipeline ----
  for (int kc = 0; kc < 8; kc++) {
#pragma unroll
    for (int t2 = 0; t2 < 2; t2++) {
      int k16 = (wv * 2 + t2) * 16;
      // B-frag: lane holds k[n=k16+l16][k=quad*8+j], limbs from global (L2)
      const size_t kb = ((size_t)bh * SS + kc * 128 + k16 + l16) * HD + quad * 8;
      bf16x8 bH0 = *(const bf16x8*)(khg + kb);
      bf16x8 bH1 = *(const bf16x8*)(khg + kb + 32);
      bf16x8 bM0 = *(const bf16x8*)(kmg + kb);
      bf16x8 bM1 = *(const bf16x8*)(kmg + kb + 32);
      bf16x8 bL0 = *(const bf16x8*)(klg + kb);
      bf16x8 bL1 = *(const bf16x8*)(klg + kb + 32);
      f32x4 accA = {}, accB = {}, accC = {};
      accA = mfma16(aH[0], bH0, accA);             // hh, k-half 0
      accB = mfma16(aH[1], bH1, accB);             // hh, k-half 1
      accC = mfma16(aH[0], bM0, accC);             // hm
      accC = mfma16(aH[1], bM1, accC);
      accC = mfma16(aM[0], bH0, accC);             // mh
      accC = mfma16(aM[1], bH1, accC);
      accC = mfma16(aH[0], bL0, accC);             // hl
      accC = mfma16(aH[1], bL1, accC);
      accC = mfma16(aL[0], bH0, accC);             // lh
      accC = mfma16(aL[1], bH1, accC);
      accC = mfma16(aM[0], bM0, accC);             // mm
      accC = mfma16(aM[1], bM1, accC);
      if (quad < 2) {                              // rows 0..7 valid
        int key = kc * 128 + k16 + l16;
#pragma unroll
        for (int r = 0; r < 4; r++)
          sc[(quad * 4 + r) * 1028 + key] = ((accA[r] + accB[r]) + accC[r]) * 0.125f;
      }
    }
  }
  __syncthreads();

  // ---- selection + softmax: wave wv handles queries wv, wv+4 ----
  uint32_t* histw = hist + wv * 256;
  const uint64_t lt = (1ull << lane) - 1ull;
  for (int qi = 0; qi < 2; qi++) {
    int q = qi * 4 + wv;
    float* row = sc + q * 1028;
    float fv[16];
#pragma unroll
    for (int i = 0; i < 16; i++) fv[i] = row[i * 64 + lane];
    uint32_t prefix = 0, pmask = 0;
    int needed = 64;
    for (int rnd = 0; rnd < 4; rnd++) {
      int shift = 24 - rnd * 8;
      *(uint4*)(histw + lane * 4) = uint4{0, 0, 0, 0};
      wave_fence();
#pragma unroll
      for (int i = 0; i < 16; i++) {
        uint32_t u = fkey(fv[i]);
        if ((u & pmask) == prefix) atomicAdd(histw + ((u >> shift) & 255u), 1u);
      }
      wave_fence();
      // descending cumulative scan: lane covers bins 255-4l .. 252-4l
      uint4 hv = *(const uint4*)(histw + (252 - lane * 4));
      uint32_t s_l = hv.x + hv.y + hv.z + hv.w;
      uint32_t x = s_l;
#pragma unroll
      for (int off = 1; off < 64; off <<= 1) {
        uint32_t y = __shfl_up(x, off);
        if (lane >= off) x += y;
      }
      uint32_t P = x - s_l;  // count in bins strictly above this lane's range
      uint32_t harr[4] = { hv.w, hv.z, hv.y, hv.x };  // c=0 -> bin 255-4l
      uint32_t cb = P, G = 0;
      int foundc = -1;
#pragma unroll
      for (int c = 0; c < 4; c++) {
        uint32_t hc = harr[c];
        if (foundc < 0 && (int)cb < needed && (int)(cb + hc) >= needed) {
          foundc = c; G = cb;
        }
        cb += hc;
      }
      uint64_t fm = __ballot(foundc >= 0);
      int src = __ffsll((unsigned long long)fm) - 1;
      int vstar = __shfl((foundc >= 0) ? (255 - lane * 4 - foundc) : 0, src);
      int Gs    = __shfl((int)G, src);
      needed -= Gs;
      prefix |= ((uint32_t)vstar) << shift;
      pmask  |= 0xFFu << shift;
      wave_fence();
    }
    // gather: u>T always; u==T taken in ascending index order (jax tie-break)
    int selTotal = 0, eqTaken = 0;
#pragma unroll
    for (int i = 0; i < 16; i++) {
      int idx = i * 64 + lane;
      float f = fv[i];
      uint32_t u = fkey(f);
      bool isG = u > prefix, isE = (u == prefix);
      uint64_t em = __ballot(isE);
      int eqrank = eqTaken + (int)__popcll(em & lt);
      bool s_ = isG || (isE && eqrank < needed);
      uint64_t sm = __ballot(s_);
      int pos = selTotal + (int)__popcll(sm & lt);
      if (s_) { selIdx[q * 64 + pos] = (ushort)idx; selW[q * 64 + pos] = f; }
      selTotal += (int)__popcll(sm);
      eqTaken  += (int)__popcll(em);
    }
    wave_fence();
    // softmax over the 64 selected scores
    float sv = selW[q * 64 + lane];
    float mx = sv;
#pragma unroll
    for (int off = 32; off >= 1; off >>= 1) mx = fmaxf(mx, __shfl_xor(mx, off));
    float e = __expf(sv - mx);
    float sum = e;
#pragma unroll
    for (int off = 32; off >= 1; off >>= 1) sum += __shfl_xor(sum, off);
    selW[q * 64 + lane] = e / sum;
    wave_fence();
  }
  __syncthreads();   // PV reads other waves' selW/selIdx

  // ---- PV: thread t -> (q = t>>4, d-block = (t&15)*4); split-2 write ----
  if (tid < 128) {
    int q = tid >> 4, dblk = (tid & 15) * 4;
    const float* vb = vg + (size_t)bh * SS * HD;
    f32x4 a4 = {};
    for (int j = 0; j < 64; j++) {
      float w = selW[q * 64 + j];
      int  idx = selIdx[q * 64 + j];
      f32x4 v4 = *(const f32x4*)(vb + (size_t)idx * HD + dblk);
      a4 += w * v4;
    }
    size_t dofs = ((size_t)b_ * SS + q0 + q) * EE + h_ * HD + dblk;
    bf16x4 oh, om;
#pragma unroll
    for (int j = 0; j < 4; j++) {
      bf16_t hh = (bf16_t)a4[j];
      oh[j] = hh;
      om[j] = (bf16_t)(a4[j] - (float)hh);
    }
    *(bf16x4*)(attnH + dofs) = oh;
    *(bf16x4*)(attnM + dofs) = om;
  }
}

// ---------------------------------------------------------------------------
extern "C" void kernel_launch(void* const* d_in, const int* in_sizes, int n_in,
                              void* d_out, int out_size, void* d_ws, size_t ws_size,
                              hipStream_t stream)
{
  const float* x  = (const float*)d_in[0];
  const float* Wq = (const float*)d_in[1];
  const float* bq = (const float*)d_in[2];
  const float* Wk = (const float*)d_in[3];
  const float* bk = (const float*)d_in[4];
  const float* Wv = (const float*)d_in[5];
  const float* bv = (const float*)d_in[6];
  const float* Wo = (const float*)d_in[7];
  const float* bo = (const float*)d_in[8];

  // ws layout (bf16 elems from base) — must match presplit_all's offsets:
  // x limbs @0..3NX | Wq @3NX | Wk @3NX+3NW | Wv @3NX+6NW | Wo @3NX+9NW
  bf16_t* base = (bf16_t*)d_ws;
  bf16_t *xh = base,            *xm = xh + NX_,  *xl = xm + NX_;
  bf16_t *wqh = base + 3*NX_,           *wqm = wqh + NW_, *wql = wqm + NW_;
  bf16_t *wkh = base + 3*NX_ + 3*NW_,   *wkm = wkh + NW_, *wkl = wkm + NW_;
  bf16_t *wvh = base + 3*NX_ + 6*NW_,   *wvm = wvh + NW_, *wvl = wvm + NW_;
  bf16_t *woh = base + 3*NX_ + 9*NW_,   *wom = woh + NW_, *wol = wom + NW_;
  bf16_t *p2 = base + 3*NX_ + 12*NW_;
  bf16_t *qh = p2,          *qm = qh + NX_, *ql = qm + NX_;
  bf16_t *kh = ql + NX_,    *km = kh + NX_, *kl = km + NX_;
  float  *vws = (float*)(kl + NX_);
  bf16_t *ath = (bf16_t*)(vws + NX_), *atm = ath + NX_;

  dim3 blk(256);
  presplit_all<<<dim3(6144), blk, 0, stream>>>(x, Wq, Wk, Wv, Wo, base);

  dim3 gg(EE / 64, (NB * SS) / 64);                 // 16 x 32 tiles
  gemm_pre<0, 6><<<gg, blk, 0, stream>>>(xh, xm, xl, wqh, wqm, wql, bq,
                                         qh, qm, ql, nullptr);
  gemm_pre<0, 6><<<gg, blk, 0, stream>>>(xh, xm, xl, wkh, wkm, wkl, bk,
                                         kh, km, kl, nullptr);
  gemm_pre<1, 3><<<gg, blk, 0, stream>>>(xh, xm, xl, wvh, wvm, wvl, bv,
                                         nullptr, nullptr, nullptr, vws);

  attn_topk<<<dim3(NBH * (SS / 8)), blk, 0, stream>>>(qh, qm, ql, kh, km, kl,
                                                      vws, ath, atm);

  gemm_pre<2, 3><<<gg, blk, 0, stream>>>(ath, atm, nullptr, woh, wom, wol, bo,
                                         nullptr, nullptr, nullptr, (float*)d_out);
}

// Round 5
// 374.396 us; speedup vs baseline: 1.9199x; 1.2034x over previous
//
#include <hip/hip_runtime.h>
#include <hip/hip_bf16.h>
#include <stdint.h>

// DynamicSparseAttention MI355X r5 — fp32 I/O.
// r4 passed @450us (attn 243us, latency-bound, FETCH 88MB = 2.7x overfetch
// from cross-XCD L2 thrash). r5 attn restructure:
//   - XCD swizzle: bh -> fixed XCD (blockIdx%8), per-XCD set ~4MB = L2-resident
//   - 16 q/WG, 512 thr / 8 waves: full MFMA M-rows (was 8/16), k-traffic/q halved
//   - register double-buffer k-frag prefetch; PV gather split 2x + shfl combine
// GEMMs/presplit unchanged from r4 (next round's target).

typedef __bf16 bf16_t;
typedef bf16_t bf16x8 __attribute__((ext_vector_type(8)));
typedef bf16_t bf16x4 __attribute__((ext_vector_type(4)));
typedef float  f32x4  __attribute__((ext_vector_type(4)));

#define NB 2
#define SS 1024
#define EE 1024
#define NH 16
#define HD 64
#define NBH (NB*NH)
#define NX_ ((size_t)NB*SS*EE)   // 2,097,152
#define NW_ ((size_t)EE*EE)      // 1,048,576

__device__ __forceinline__ f32x4 mfma16(bf16x8 a, bf16x8 b, f32x4 c) {
  return __builtin_amdgcn_mfma_f32_16x16x32_bf16(a, b, c, 0, 0, 0);
}

// monotone key: larger float -> larger uint
__device__ __forceinline__ uint32_t fkey(float f) {
  uint32_t u = __float_as_uint(f);
  return (u & 0x80000000u) ? ~u : (u | 0x80000000u);
}

__device__ __forceinline__ void split3(float x, bf16_t& h, bf16_t& m, bf16_t& l) {
  h = (bf16_t)x;
  float r = x - (float)h;     // exact
  m = (bf16_t)r;
  float r2 = r - (float)m;    // exact
  l = (bf16_t)r2;             // residual <= 2^-27 |x|
}

// wave-local LDS ordering fence (per-wave hist/sel; no cross-wave deps)
__device__ __forceinline__ void wave_fence() {
  __builtin_amdgcn_wave_barrier();
  __builtin_amdgcn_s_waitcnt(0);
  __builtin_amdgcn_wave_barrier();
}

// ---------------------------------------------------------------------------
// fused presplit of x, Wq, Wk, Wv, Wo into h/m/l limb arrays (r4, unchanged)
// ---------------------------------------------------------------------------
__global__ __launch_bounds__(256) void presplit_all(
    const float* __restrict__ x,  const float* __restrict__ wq,
    const float* __restrict__ wk, const float* __restrict__ wv,
    const float* __restrict__ wo, bf16_t* __restrict__ base)
{
  const int blk = blockIdx.x;
  const float* src; bf16_t* h; size_t n; int i;
  if (blk < 2048)      { src = x;  h = base;                   n = NX_; i = blk;        }
  else if (blk < 3072) { src = wq; h = base + 3*NX_;           n = NW_; i = blk - 2048; }
  else if (blk < 4096) { src = wk; h = base + 3*NX_ + 3*NW_;   n = NW_; i = blk - 3072; }
  else if (blk < 5120) { src = wv; h = base + 3*NX_ + 6*NW_;   n = NW_; i = blk - 4096; }
  else                 { src = wo; h = base + 3*NX_ + 9*NW_;   n = NW_; i = blk - 5120; }
  bf16_t* m = h + n;
  bf16_t* l = m + n;
  int idx = i * 256 + threadIdx.x;            // float4 index
  float4 v = ((const float4*)src)[idx];
  float t[4] = { v.x, v.y, v.z, v.w };
  bf16x4 hv, mv, lv;
#pragma unroll
  for (int j = 0; j < 4; j++) {
    bf16_t a, b, c;
    split3(t[j], a, b, c);
    hv[j] = a; mv[j] = b; lv[j] = c;
  }
  ((bf16x4*)h)[idx] = hv;
  ((bf16x4*)m)[idx] = mv;
  ((bf16x4*)l)[idx] = lv;
}

// ---------------------------------------------------------------------------
// NT GEMM on pre-split operands (r3/r4, unchanged)
// ---------------------------------------------------------------------------
template<int MODE, int NT>
__global__ __launch_bounds__(256) void gemm_pre(
    const bf16_t* __restrict__ Ah, const bf16_t* __restrict__ Am,
    const bf16_t* __restrict__ Al,
    const bf16_t* __restrict__ Bh, const bf16_t* __restrict__ Bm,
    const bf16_t* __restrict__ Bl,
    const float* __restrict__ bias,
    bf16_t* __restrict__ dH, bf16_t* __restrict__ dM, bf16_t* __restrict__ dL,
    float* __restrict__ dF)
{
  __shared__ bf16_t AsH[64 * 40], AsM[64 * 40], AsL[64 * 40];
  __shared__ bf16_t BsH[64 * 40], BsM[64 * 40], BsL[64 * 40];

  const int tid  = threadIdx.x;
  const int wv   = tid >> 6, lane = tid & 63;
  const int quad = lane >> 4, l16 = lane & 15;
  const int m0 = blockIdx.y * 64, n0 = blockIdx.x * 64;
  const int wm = (wv & 1) * 32, wn = (wv >> 1) * 32;
  const int srow = tid >> 2, scol = (tid & 3) * 8;

  f32x4 aH0[2][2] = {};   // hh accumulator, k < 512
  f32x4 aH1[2][2] = {};   // hh accumulator, k >= 512
  f32x4 aC [2][2] = {};   // correction terms (small magnitude)

  for (int k0 = 0; k0 < 1024; k0 += 32) {
    const size_t ao = (size_t)(m0 + srow) * 1024 + k0 + scol;
    const size_t bo = (size_t)(n0 + srow) * 1024 + k0 + scol;
    bf16x8 avh = *(const bf16x8*)(Ah + ao);
    bf16x8 avm = *(const bf16x8*)(Am + ao);
    bf16x8 bvh = *(const bf16x8*)(Bh + bo);
    bf16x8 bvm = *(const bf16x8*)(Bm + bo);
    bf16x8 avl, bvl;
    if (NT == 6) { avl = *(const bf16x8*)(Al + ao); bvl = *(const bf16x8*)(Bl + bo); }
    __syncthreads();                      // protect previous iter frag reads
    *(bf16x8*)(AsH + srow * 40 + scol) = avh;
    *(bf16x8*)(AsM + srow * 40 + scol) = avm;
    *(bf16x8*)(BsH + srow * 40 + scol) = bvh;
    *(bf16x8*)(BsM + srow * 40 + scol) = bvm;
    if (NT == 6) {
      *(bf16x8*)(AsL + srow * 40 + scol) = avl;
      *(bf16x8*)(BsL + srow * 40 + scol) = bvl;
    }
    __syncthreads();

    bf16x8 fAh[2], fAm[2], fAl[2], fBh[2], fBm[2], fBl[2];
#pragma unroll
    for (int t = 0; t < 2; t++) {
      fAh[t] = *(const bf16x8*)(AsH + (wm + t * 16 + l16) * 40 + quad * 8);
      fAm[t] = *(const bf16x8*)(AsM + (wm + t * 16 + l16) * 40 + quad * 8);
      fBh[t] = *(const bf16x8*)(BsH + (wn + t * 16 + l16) * 40 + quad * 8);
      fBm[t] = *(const bf16x8*)(BsM + (wn + t * 16 + l16) * 40 + quad * 8);
      if (NT == 6) {
        fAl[t] = *(const bf16x8*)(AsL + (wm + t * 16 + l16) * 40 + quad * 8);
        fBl[t] = *(const bf16x8*)(BsL + (wn + t * 16 + l16) * 40 + quad * 8);
      }
    }
    const bool hi = (k0 >= 512);
#pragma unroll
    for (int mt = 0; mt < 2; mt++)
#pragma unroll
    for (int nt = 0; nt < 2; nt++) {
      f32x4& H = hi ? aH1[mt][nt] : aH0[mt][nt];
      H = mfma16(fAh[mt], fBh[nt], H);
      aC[mt][nt] = mfma16(fAh[mt], fBm[nt], aC[mt][nt]);
      aC[mt][nt] = mfma16(fAm[mt], fBh[nt], aC[mt][nt]);
      if (NT == 6) {
        aC[mt][nt] = mfma16(fAh[mt], fBl[nt], aC[mt][nt]);
        aC[mt][nt] = mfma16(fAl[mt], fBh[nt], aC[mt][nt]);
        aC[mt][nt] = mfma16(fAm[mt], fBm[nt], aC[mt][nt]);
      }
    }
  }

  // epilogue: D[row=quad*4+r][col=l16]
#pragma unroll
  for (int mt = 0; mt < 2; mt++)
#pragma unroll
  for (int nt = 0; nt < 2; nt++)
#pragma unroll
  for (int r  = 0; r  < 4;  r++) {
    int gm = m0 + wm + mt * 16 + quad * 4 + r;
    int gn = n0 + wn + nt * 16 + l16;
    float v = (aH0[mt][nt][r] + aH1[mt][nt][r]) + aC[mt][nt][r] + bias[gn];
    if (MODE == 2) {
      dF[(size_t)gm * 1024 + gn] = v;
    } else {
      int b_ = gm >> 10, s_ = gm & 1023, h_ = gn >> 6, d_ = gn & 63;
      size_t di = (((size_t)b_ * NH + h_) * SS + s_) * HD + d_;
      if (MODE == 1) {
        dF[di] = v;
      } else {
        bf16_t hh, mm, ll;
        split3(v, hh, mm, ll);
        dH[di] = hh; dM[di] = mm; dL[di] = ll;
      }
    }
  }
}

// ---------------------------------------------------------------------------
// Fused attention r5: per WG = one (b,h) x 16 queries, 512 threads / 8 waves.
// XCD-swizzled blockIdx (bh pinned to XCD -> L2-resident k/q/v).
// Wave wv owns keys [wv*128, wv*128+128): 8 x 12 MFMA with register
// double-buffered k-frag prefetch. Exact top-64 radix select -> softmax -> PV.
// LDS: sc 65792 + hist 8192 + selIdx 2048 + selW 4096 = 80128 B -> 2 WG/CU.
// ---------------------------------------------------------------------------
__global__ __launch_bounds__(512, 4) void attn_topk(
    const bf16_t* __restrict__ qhg, const bf16_t* __restrict__ qmg,
    const bf16_t* __restrict__ qlg,
    const bf16_t* __restrict__ khg, const bf16_t* __restrict__ kmg,
    const bf16_t* __restrict__ klg,
    const float*  __restrict__ vg,
    bf16_t* __restrict__ attnH, bf16_t* __restrict__ attnM)
{
  __shared__ float    sc[16 * 1028];      // stride 1028 = 4 mod 32 banks
  __shared__ uint32_t hist[8 * 256];      // per-wave radix histograms
  __shared__ ushort   selIdx[16 * 64];
  __shared__ float    selW[16 * 64];

  const int tid  = threadIdx.x;
  const int wv   = tid >> 6, lane = tid & 63;
  const int quad = lane >> 4, l16 = lane & 15;
  // XCD swizzle: blocks with blockIdx%8==x serve bh in {x,x+8,x+16,x+24}
  const int xcd = blockIdx.x & 7;
  const int g   = blockIdx.x >> 3;        // 0..255
  const int bh  = xcd + 8 * (g >> 6);     // 0..31
  const int qt  = g & 63;                 // 0..63
  const int b_ = bh >> 4, h_ = bh & 15;
  const int q0 = qt * 16;

  // A-frags direct from global: lane holds q[m=l16][k=quad*8+j], 16 valid rows
  const size_t qbase = ((size_t)bh * SS + q0 + l16) * HD + quad * 8;
  bf16x8 aH[2], aM[2], aL[2];
#pragma unroll
  for (int ks = 0; ks < 2; ks++) {
    aH[ks] = *(const bf16x8*)(qhg + qbase + ks * 32);
    aM[ks] = *(const bf16x8*)(qmg + qbase + ks * 32);
    aL[ks] = *(const bf16x8*)(qlg + qbase + ks * 32);
  }

  // ---- score phase: wave wv covers keys [wv*128, wv*128+128), 16 per iter --
  // frag index: [0]=H0 [1]=H1 [2]=M0 [3]=M1 [4]=L0 [5]=L1
  const size_t kwb = ((size_t)bh * SS + wv * 128 + l16) * HD + quad * 8;
  bf16x8 cur[6], nxt[6];
  {
    const size_t kb = kwb;                               // t2 = 0
    cur[0] = *(const bf16x8*)(khg + kb);
    cur[1] = *(const bf16x8*)(khg + kb + 32);
    cur[2] = *(const bf16x8*)(kmg + kb);
    cur[3] = *(const bf16x8*)(kmg + kb + 32);
    cur[4] = *(const bf16x8*)(klg + kb);
    cur[5] = *(const bf16x8*)(klg + kb + 32);
  }
#pragma unroll 2
  for (int t2 = 0; t2 < 8; t2++) {
    if (t2 < 7) {
      const size_t kb = kwb + (size_t)(t2 + 1) * 16 * HD;
      nxt[0] = *(const bf16x8*)(khg + kb);
      nxt[1] = *(const bf16x8*)(khg + kb + 32);
      nxt[2] = *(const bf16x8*)(kmg + kb);
      nxt[3] = *(const bf16x8*)(kmg + kb + 32);
      nxt[4] = *(const bf16x8*)(klg + kb);
      nxt[5] = *(const bf16x8*)(klg + kb + 32);
    }
    f32x4 accA = {}, accB = {}, accC = {};
    accA = mfma16(aH[0], cur[0], accA);            // hh, k-half 0
    accB = mfma16(aH[1], cur[1], accB);            // hh, k-half 1
    accC = mfma16(aH[0], cur[2], accC);            // hm
    accC = mfma16(aH[1], cur[3], accC);
    accC = mfma16(aM[0], cur[0], accC);            // mh
    accC = mfma16(aM[1], cur[1], accC);
    accC = mfma16(aH[0], cur[4], accC);            // hl
    accC = mfma16(aH[1], cur[5], accC);
    accC = mfma16(aL[0], cur[0], accC);            // lh
    accC = mfma16(aL[1], cur[1], accC);
    accC = mfma16(aM[0], cur[2], accC);            // mm
    accC = mfma16(aM[1], cur[3], accC);
    int key = wv * 128 + t2 * 16 + l16;
#pragma unroll
    for (int r = 0; r < 4; r++)
      sc[(quad * 4 + r) * 1028 + key] = ((accA[r] + accB[r]) + accC[r]) * 0.125f;
#pragma unroll
    for (int f = 0; f < 6; f++) cur[f] = nxt[f];
  }
  __syncthreads();

  // ---- selection + softmax: wave wv handles queries wv, wv+8 ----
  uint32_t* histw = hist + wv * 256;
  const uint64_t lt = (1ull << lane) - 1ull;
  for (int qi = 0; qi < 2; qi++) {
    int q = qi * 8 + wv;
    float* row = sc + q * 1028;
    float fv[16];
#pragma unroll
    for (int i = 0; i < 16; i++) fv[i] = row[i * 64 + lane];
    uint32_t prefix = 0, pmask = 0;
    int needed = 64;
    for (int rnd = 0; rnd < 4; rnd++) {
      int shift = 24 - rnd * 8;
      *(uint4*)(histw + lane * 4) = uint4{0, 0, 0, 0};
      wave_fence();
#pragma unroll
      for (int i = 0; i < 16; i++) {
        uint32_t u = fkey(fv[i]);
        if ((u & pmask) == prefix) atomicAdd(histw + ((u >> shift) & 255u), 1u);
      }
      wave_fence();
      // descending cumulative scan: lane covers bins 255-4l .. 252-4l
      uint4 hv = *(const uint4*)(histw + (252 - lane * 4));
      uint32_t s_l = hv.x + hv.y + hv.z + hv.w;
      uint32_t x = s_l;
#pragma unroll
      for (int off = 1; off < 64; off <<= 1) {
        uint32_t y = __shfl_up(x, off);
        if (lane >= off) x += y;
      }
      uint32_t P = x - s_l;  // count in bins strictly above this lane's range
      uint32_t harr[4] = { hv.w, hv.z, hv.y, hv.x };  // c=0 -> bin 255-4l
      uint32_t cb = P, G = 0;
      int foundc = -1;
#pragma unroll
      for (int c = 0; c < 4; c++) {
        uint32_t hc = harr[c];
        if (foundc < 0 && (int)cb < needed && (int)(cb + hc) >= needed) {
          foundc = c; G = cb;
        }
        cb += hc;
      }
      uint64_t fm = __ballot(foundc >= 0);
      int src = __ffsll((unsigned long long)fm) - 1;
      int vstar = __shfl((foundc >= 0) ? (255 - lane * 4 - foundc) : 0, src);
      int Gs    = __shfl((int)G, src);
      needed -= Gs;
      prefix |= ((uint32_t)vstar) << shift;
      pmask  |= 0xFFu << shift;
      wave_fence();
    }
    // gather: u>T always; u==T taken in ascending index order (jax tie-break)
    int selTotal = 0, eqTaken = 0;
#pragma unroll
    for (int i = 0; i < 16; i++) {
      int idx = i * 64 + lane;
      float f = fv[i];
      uint32_t u = fkey(f);
      bool isG = u > prefix, isE = (u == prefix);
      uint64_t em = __ballot(isE);
      int eqrank = eqTaken + (int)__popcll(em & lt);
      bool s_ = isG || (isE && eqrank < needed);
      uint64_t sm = __ballot(s_);
      int pos = selTotal + (int)__popcll(sm & lt);
      if (s_) { selIdx[q * 64 + pos] = (ushort)idx; selW[q * 64 + pos] = f; }
      selTotal += (int)__popcll(sm);
      eqTaken  += (int)__popcll(em);
    }
    wave_fence();
    // softmax over the 64 selected scores
    float sv = selW[q * 64 + lane];
    float mx = sv;
#pragma unroll
    for (int off = 32; off >= 1; off >>= 1) mx = fmaxf(mx, __shfl_xor(mx, off));
    float e = __expf(sv - mx);
    float sum = e;
#pragma unroll
    for (int off = 32; off >= 1; off >>= 1) sum += __shfl_xor(sum, off);
    selW[q * 64 + lane] = e / sum;
    wave_fence();
  }
  __syncthreads();   // PV reads other waves' selW/selIdx

  // ---- PV: thread t -> q = t>>5, j-half = (t>>4)&1, d-block = (t&15)*4 ----
  {
    int q = tid >> 5, jh = (tid >> 4) & 1, dblk = (tid & 15) * 4;
    const float* vb = vg + (size_t)bh * SS * HD;
    f32x4 a4 = {};
#pragma unroll 4
    for (int j = 0; j < 32; j++) {
      int jj = jh * 32 + j;
      float w = selW[q * 64 + jj];
      int  idx = selIdx[q * 64 + jj];
      f32x4 v4 = *(const f32x4*)(vb + (size_t)idx * HD + dblk);
      a4 += w * v4;
    }
    // combine j-halves: partner thread is tid^16 (same wave)
#pragma unroll
    for (int c = 0; c < 4; c++) a4[c] += __shfl_xor(a4[c], 16);
    if (jh == 0) {
      size_t dofs = ((size_t)b_ * SS + q0 + q) * EE + h_ * HD + dblk;
      bf16x4 oh, om;
#pragma unroll
      for (int j = 0; j < 4; j++) {
        bf16_t hh = (bf16_t)a4[j];
        oh[j] = hh;
        om[j] = (bf16_t)(a4[j] - (float)hh);
      }
      *(bf16x4*)(attnH + dofs) = oh;
      *(bf16x4*)(attnM + dofs) = om;
    }
  }
}

// ---------------------------------------------------------------------------
extern "C" void kernel_launch(void* const* d_in, const int* in_sizes, int n_in,
                              void* d_out, int out_size, void* d_ws, size_t ws_size,
                              hipStream_t stream)
{
  const float* x  = (const float*)d_in[0];
  const float* Wq = (const float*)d_in[1];
  const float* bq = (const float*)d_in[2];
  const float* Wk = (const float*)d_in[3];
  const float* bk = (const float*)d_in[4];
  const float* Wv = (const float*)d_in[5];
  const float* bv = (const float*)d_in[6];
  const float* Wo = (const float*)d_in[7];
  const float* bo = (const float*)d_in[8];

  // ws layout (bf16 elems from base) — must match presplit_all's offsets:
  bf16_t* base = (bf16_t*)d_ws;
  bf16_t *xh = base,            *xm = xh + NX_,  *xl = xm + NX_;
  bf16_t *wqh = base + 3*NX_,           *wqm = wqh + NW_, *wql = wqm + NW_;
  bf16_t *wkh = base + 3*NX_ + 3*NW_,   *wkm = wkh + NW_, *wkl = wkm + NW_;
  bf16_t *wvh = base + 3*NX_ + 6*NW_,   *wvm = wvh + NW_, *wvl = wvm + NW_;
  bf16_t *woh = base + 3*NX_ + 9*NW_,   *wom = woh + NW_, *wol = wom + NW_;
  bf16_t *p2 = base + 3*NX_ + 12*NW_;
  bf16_t *qh = p2,          *qm = qh + NX_, *ql = qm + NX_;
  bf16_t *kh = ql + NX_,    *km = kh + NX_, *kl = km + NX_;
  float  *vws = (float*)(kl + NX_);
  bf16_t *ath = (bf16_t*)(vws + NX_), *atm = ath + NX_;

  dim3 blk(256);
  presplit_all<<<dim3(6144), blk, 0, stream>>>(x, Wq, Wk, Wv, Wo, base);

  dim3 gg(EE / 64, (NB * SS) / 64);                 // 16 x 32 tiles
  gemm_pre<0, 6><<<gg, blk, 0, stream>>>(xh, xm, xl, wqh, wqm, wql, bq,
                                         qh, qm, ql, nullptr);
  gemm_pre<0, 6><<<gg, blk, 0, stream>>>(xh, xm, xl, wkh, wkm, wkl, bk,
                                         kh, km, kl, nullptr);
  gemm_pre<1, 3><<<gg, blk, 0, stream>>>(xh, xm, xl, wvh, wvm, wvl, bv,
                                         nullptr, nullptr, nullptr, vws);

  attn_topk<<<dim3(NBH * (SS / 16)), dim3(512), 0, stream>>>(
      qh, qm, ql, kh, km, kl, vws, ath, atm);

  gemm_pre<2, 3><<<gg, blk, 0, stream>>>(ath, atm, nullptr, woh, wom, wol, bo,
                                         nullptr, nullptr, nullptr, (float*)d_out);
}